// Round 1
// baseline (178.137 us; speedup 1.0000x reference)
//
#include <hip/hip_runtime.h>
#include <hip/hip_bf16.h>

typedef __bf16 bf16;
typedef __attribute__((ext_vector_type(8))) __bf16 bf16x8;
typedef __attribute__((ext_vector_type(4))) __bf16 bf16x4;
typedef __attribute__((ext_vector_type(4))) float f32x4;

#define M_DIM 8192
#define K_DIM 1024
#define N_DIM 4096
#define OUT_ELEMS (M_DIM * (size_t)N_DIM)

static __device__ __forceinline__ void gload_lds16(const void* g, void* l) {
  __builtin_amdgcn_global_load_lds((__attribute__((address_space(1))) void*)g,
                                   (__attribute__((address_space(3))) void*)l,
                                   16, 0, 0);
}

// monotone float<->uint encoding for atomic min/max
static __device__ __forceinline__ unsigned enc(float f) {
  unsigned u = __float_as_uint(f);
  return (u >> 31) ? ~u : (u ^ 0x80000000u);
}
static __device__ __forceinline__ float dec(unsigned e) {
  return (e >> 31) ? __uint_as_float(e ^ 0x80000000u) : __uint_as_float(~e);
}

// -------- Kernel A: per-channel weight quant + IntGELU per-channel constants --------
__global__ __launch_bounds__(256) void k_prep_w(
    const float* __restrict__ w, const float* __restrict__ bias,
    const float* __restrict__ prev_sf,
    bf16* __restrict__ wq, float* __restrict__ pb, float* __restrict__ pbg,
    float* __restrict__ pcg, float* __restrict__ psh, float* __restrict__ posf,
    unsigned* __restrict__ mm) {
  const int o = blockIdx.x;
  const int t = threadIdx.x;
  const float4 wv = *(const float4*)(w + (size_t)o * K_DIM + t * 4);
  float m = fmaxf(fmaxf(fabsf(wv.x), fabsf(wv.y)), fmaxf(fabsf(wv.z), fabsf(wv.w)));
  __shared__ float red[256];
  red[t] = m;
  __syncthreads();
  for (int s = 128; s > 0; s >>= 1) {
    if (t < s) red[t] = fmaxf(red[t], red[t + s]);
    __syncthreads();
  }
  const float fc = fmaxf(red[0], 1e-8f) / 127.f;  // fc_sf[o]
  bf16x4 q;
  q[0] = (bf16)fminf(fmaxf(rintf(wv.x / fc), -127.f), 126.f);
  q[1] = (bf16)fminf(fmaxf(rintf(wv.y / fc), -127.f), 126.f);
  q[2] = (bf16)fminf(fmaxf(rintf(wv.z / fc), -127.f), 126.f);
  q[3] = (bf16)fminf(fmaxf(rintf(wv.w / fc), -127.f), 126.f);
  *(bf16x4*)(wq + (size_t)o * K_DIM + t * 4) = q;
  if (t == 0) {
    const float psf = prev_sf[0];
    const float bsf = fc * psf;  // bias_sf
    float bi = fminf(fmaxf(rintf(bias[o] / bsf), -2147483647.f), 2147483646.f);
    const float sfe = bsf / 1.4142f;
    const float bg = floorf(-1.769f / sfe);
    const float cF = (float)(1.0 / -0.2888);
    const float se2 = sfe * sfe;
    const float cg = floorf(cF / se2);
    const float sig = (se2 * -0.2888f) * 16384.f;   // sf_e^2 * a * 2^14
    const float sh = floorf(1.0f / sig);            // shift (negative)
    const float osf = (bsf * sig) * 0.5f;           // out_sf (negative)
    pb[o] = bi; pbg[o] = bg; pcg[o] = cg; psh[o] = sh; posf[o] = osf;
  }
  if (o == 0 && t == 0) {  // init global min/max (encoded 0.0f, matches min(.,0)/max(.,0))
    mm[0] = 0x80000000u;   // min slot
    mm[1] = 0x80000000u;   // max slot
  }
}

// -------- Kernel B: activation -> exact-integer bf16 --------
__global__ __launch_bounds__(256) void k_quant_x(
    const float* __restrict__ x, const float* __restrict__ prev_sf,
    bf16* __restrict__ xq) {
  const size_t i = ((size_t)blockIdx.x * 256 + threadIdx.x) * 4;
  const float inv = 1.0f / prev_sf[0];
  const float4 v = *(const float4*)(x + i);
  bf16x4 q;
  q[0] = (bf16)rintf(v.x * inv);
  q[1] = (bf16)rintf(v.y * inv);
  q[2] = (bf16)rintf(v.z * inv);
  q[3] = (bf16)rintf(v.w * inv);
  *(bf16x4*)(xq + i) = q;
}

// -------- Kernel C: bf16 MFMA GEMM (exact int) + fused bias + IntGELU + min/max --------
__global__ __launch_bounds__(256) void k_gemm(
    const bf16* __restrict__ A, const bf16* __restrict__ B,
    const float* __restrict__ pb, const float* __restrict__ pbg,
    const float* __restrict__ pcg, const float* __restrict__ psh,
    const float* __restrict__ posf,
    float* __restrict__ out, unsigned* __restrict__ mm) {
  __shared__ bf16 lA[128 * 64];
  __shared__ bf16 lB[128 * 64];
  const int t = threadIdx.x;
  const int wave = t >> 6, lane = t & 63;
  const int wm = wave >> 1, wn = wave & 1;
  const int brow = blockIdx.y * 128, bcol = blockIdx.x * 128;
  const int l8r = lane >> 3, l8c = lane & 7;   // staging: 8 rows x 8 lanes*16B
  const int r16 = lane & 15, q4 = lane >> 4;   // fragment coords
  f32x4 acc[4][4] = {};

  for (int kt = 0; kt < K_DIM / 64; ++kt) {
    const int k0 = kt * 64;
#pragma unroll
    for (int it = 0; it < 4; ++it) {
      const int j = wave * 4 + it;  // chunk j covers rows [j*8, j*8+8)
      gload_lds16(A + (size_t)(brow + j * 8 + l8r) * K_DIM + k0 + l8c * 8, &lA[j * 512]);
      gload_lds16(B + (size_t)(bcol + j * 8 + l8r) * K_DIM + k0 + l8c * 8, &lB[j * 512]);
    }
    __syncthreads();
#pragma unroll
    for (int kk = 0; kk < 2; ++kk) {
      bf16x8 af[4], bq[4];
#pragma unroll
      for (int i = 0; i < 4; ++i) {
        af[i] = *(const bf16x8*)&lA[(wm * 64 + i * 16 + r16) * 64 + kk * 32 + q4 * 8];
        bq[i] = *(const bf16x8*)&lB[(wn * 64 + i * 16 + r16) * 64 + kk * 32 + q4 * 8];
      }
#pragma unroll
      for (int mi = 0; mi < 4; ++mi)
#pragma unroll
        for (int ni = 0; ni < 4; ++ni)
          acc[mi][ni] = __builtin_amdgcn_mfma_f32_16x16x32_bf16(af[mi], bq[ni], acc[mi][ni], 0, 0, 0);
    }
    __syncthreads();
  }

  // epilogue: bias add + IntGELU, write pre-requant value, track min/max
  float mn = 0.f, mx = 0.f;
#pragma unroll
  for (int ni = 0; ni < 4; ++ni) {
    const int ch = bcol + wn * 64 + ni * 16 + r16;
    const float bi = pb[ch], bg = pbg[ch], cg = pcg[ch], sh = psh[ch], osf = posf[ch];
#pragma unroll
    for (int mi = 0; mi < 4; ++mi) {
      const int row0 = brow + wm * 64 + mi * 16 + q4 * 4;
#pragma unroll
      for (int r = 0; r < 4; ++r) {
        const float x0 = acc[mi][ni][r] + bi;                    // out_int (int-valued fp32)
        const float sgn = (x0 > 0.f) ? 1.f : ((x0 < 0.f) ? -1.f : 0.f);
        const float ai = fminf(fabsf(x0), -bg);
        const float tt = ai + bg;
        const float y = floorf((sgn * (tt * tt + cg)) * 6.103515625e-05f);  // /2^14, floor
        const float xval = (x0 * (y + sh)) * osf;
        mn = fminf(mn, xval);
        mx = fmaxf(mx, xval);
        out[(size_t)(row0 + r) * N_DIM + ch] = xval;
      }
    }
  }
  for (int off = 32; off > 0; off >>= 1) {
    mn = fminf(mn, __shfl_down(mn, off));
    mx = fmaxf(mx, __shfl_down(mx, off));
  }
  __shared__ float smn[4], smx[4];
  if (lane == 0) { smn[wave] = mn; smx[wave] = mx; }
  __syncthreads();
  if (t == 0) {
    mn = fminf(fminf(smn[0], smn[1]), fminf(smn[2], smn[3]));
    mx = fmaxf(fmaxf(smx[0], smx[1]), fmaxf(smx[2], smx[3]));
    atomicMin(&mm[0], enc(mn));
    atomicMax(&mm[1], enc(mx));
  }
}

// -------- Kernel D: global requant (QuantAct / FixedPointMul), in place on d_out --------
__global__ __launch_bounds__(256) void k_requant(
    float* __restrict__ out, const float* __restrict__ posf,
    const unsigned* __restrict__ mm) {
  const float xmn = dec(mm[0]);
  const float xmx = dec(mm[1]);
  const float asf = fmaxf(fmaxf(fabsf(xmn), fabsf(xmx)), 1e-8f) / 127.f;
  const size_t i = ((size_t)blockIdx.x * 256 + threadIdx.x) * 4;
  float4 xv = *(float4*)(out + i);
  const int o0 = (int)(i & (N_DIM - 1));
  const float4 sf4 = *(const float4*)(posf + o0);
  float xs[4] = {xv.x, xv.y, xv.z, xv.w};
  float ps[4] = {sf4.x, sf4.y, sf4.z, sf4.w};
  float rs[4];
#pragma unroll
  for (int r = 0; r < 4; ++r) {
    const float z = rintf(xs[r] / ps[r]);
    int e;
    const float mfr = frexpf(ps[r] / asf, &e);
    const float mi = floorf(mfr * 2147483648.f + 0.5f);
    float q = rintf((z * mi) * ldexpf(1.0f, e - 31));
    q = fminf(fmaxf(q, -128.f), 127.f);
    rs[r] = q * asf;
  }
  xv.x = rs[0]; xv.y = rs[1]; xv.z = rs[2]; xv.w = rs[3];
  *(float4*)(out + i) = xv;
  if (blockIdx.x == 0 && threadIdx.x == 0) out[OUT_ELEMS] = asf;  // trailing sf scalar
}

extern "C" void kernel_launch(void* const* d_in, const int* in_sizes, int n_in,
                              void* d_out, int out_size, void* d_ws, size_t ws_size,
                              hipStream_t stream) {
  const float* x = (const float*)d_in[0];
  const float* psf = (const float*)d_in[1];
  const float* w = (const float*)d_in[2];
  const float* bias = (const float*)d_in[3];
  float* out = (float*)d_out;
  char* ws = (char*)d_ws;

  bf16* wq = (bf16*)ws;                                   // 8 MiB
  bf16* xq = (bf16*)(ws + 8388608);                       // 16 MiB
  float* pb = (float*)(ws + 25165824);                    // 5 x 16 KiB param arrays
  float* pbg = pb + N_DIM;
  float* pcg = pb + 2 * N_DIM;
  float* psh = pb + 3 * N_DIM;
  float* posf = pb + 4 * N_DIM;
  unsigned* mm = (unsigned*)(ws + 25165824 + 5 * 16384);  // 2 x u32 min/max

  k_prep_w<<<dim3(N_DIM), dim3(256), 0, stream>>>(w, bias, psf, wq, pb, pbg, pcg, psh, posf, mm);
  k_quant_x<<<dim3((M_DIM * K_DIM) / (256 * 4)), dim3(256), 0, stream>>>(x, psf, xq);
  k_gemm<<<dim3(N_DIM / 128, M_DIM / 128), dim3(256), 0, stream>>>(xq, wq, pb, pbg, pcg, psh, posf, out, mm);
  k_requant<<<dim3(OUT_ELEMS / (256 * 4)), dim3(256), 0, stream>>>(out, posf, mm);
}

// Round 2
// 143.509 us; speedup vs baseline: 1.2413x; 1.2413x over previous
//
#include <hip/hip_runtime.h>
#include <hip/hip_bf16.h>

typedef __bf16 bf16;
typedef __attribute__((ext_vector_type(8))) __bf16 bf16x8;
typedef __attribute__((ext_vector_type(4))) __bf16 bf16x4;
typedef __attribute__((ext_vector_type(4))) float f32x4;

#define M_DIM 8192
#define K_DIM 1024
#define N_DIM 4096
#define OUT_ELEMS (M_DIM * (size_t)N_DIM)
#define SLOT_BYTES 16384  // one K-slot: 256 rows x 32 k x 2B

static __device__ __forceinline__ void gload_lds16(const void* g, void* l) {
  __builtin_amdgcn_global_load_lds((__attribute__((address_space(1))) void*)g,
                                   (__attribute__((address_space(3))) void*)l,
                                   16, 0, 0);
}

// monotone float<->uint encoding for atomic min/max
static __device__ __forceinline__ unsigned enc(float f) {
  unsigned u = __float_as_uint(f);
  return (u >> 31) ? ~u : (u ^ 0x80000000u);
}
static __device__ __forceinline__ float dec(unsigned e) {
  return (e >> 31) ? __uint_as_float(e ^ 0x80000000u) : __uint_as_float(~e);
}

// -------- Kernel A: per-channel weight quant + IntGELU per-channel constants --------
__global__ __launch_bounds__(256) void k_prep_w(
    const float* __restrict__ w, const float* __restrict__ bias,
    const float* __restrict__ prev_sf,
    bf16* __restrict__ wq, float* __restrict__ pb, float* __restrict__ pbg,
    float* __restrict__ pcg, float* __restrict__ psh, float* __restrict__ posf,
    unsigned* __restrict__ mm) {
  const int o = blockIdx.x;
  const int t = threadIdx.x;
  const float4 wv = *(const float4*)(w + (size_t)o * K_DIM + t * 4);
  float m = fmaxf(fmaxf(fabsf(wv.x), fabsf(wv.y)), fmaxf(fabsf(wv.z), fabsf(wv.w)));
  __shared__ float red[256];
  red[t] = m;
  __syncthreads();
  for (int s = 128; s > 0; s >>= 1) {
    if (t < s) red[t] = fmaxf(red[t], red[t + s]);
    __syncthreads();
  }
  const float fc = fmaxf(red[0], 1e-8f) / 127.f;  // fc_sf[o]
  bf16x4 q;
  q[0] = (bf16)fminf(fmaxf(rintf(wv.x / fc), -127.f), 126.f);
  q[1] = (bf16)fminf(fmaxf(rintf(wv.y / fc), -127.f), 126.f);
  q[2] = (bf16)fminf(fmaxf(rintf(wv.z / fc), -127.f), 126.f);
  q[3] = (bf16)fminf(fmaxf(rintf(wv.w / fc), -127.f), 126.f);
  *(bf16x4*)(wq + (size_t)o * K_DIM + t * 4) = q;
  if (t == 0) {
    const float psf = prev_sf[0];
    const float bsf = fc * psf;  // bias_sf
    float bi = fminf(fmaxf(rintf(bias[o] / bsf), -2147483647.f), 2147483646.f);
    const float sfe = bsf / 1.4142f;
    const float bg = floorf(-1.769f / sfe);
    const float cF = (float)(1.0 / -0.2888);
    const float se2 = sfe * sfe;
    const float cg = floorf(cF / se2);
    const float sig = (se2 * -0.2888f) * 16384.f;   // sf_e^2 * a * 2^14
    const float sh = floorf(1.0f / sig);            // shift (negative)
    const float osf = (bsf * sig) * 0.5f;           // out_sf (negative)
    pb[o] = bi; pbg[o] = bg; pcg[o] = cg; psh[o] = sh; posf[o] = osf;
  }
  if (o == 0 && t == 0) {  // init global min/max (encoded 0.0f, matches min(.,0)/max(.,0))
    mm[0] = 0x80000000u;   // min slot
    mm[1] = 0x80000000u;   // max slot
  }
}

// -------- Kernel B: activation -> exact-integer bf16 --------
__global__ __launch_bounds__(256) void k_quant_x(
    const float* __restrict__ x, const float* __restrict__ prev_sf,
    bf16* __restrict__ xq) {
  const size_t i = ((size_t)blockIdx.x * 256 + threadIdx.x) * 4;
  const float inv = 1.0f / prev_sf[0];
  const float4 v = *(const float4*)(x + i);
  bf16x4 q;
  q[0] = (bf16)rintf(v.x * inv);
  q[1] = (bf16)rintf(v.y * inv);
  q[2] = (bf16)rintf(v.z * inv);
  q[3] = (bf16)rintf(v.w * inv);
  *(bf16x4*)(xq + i) = q;
}

// -------- Kernel C: 256x256-tile pipelined bf16 MFMA GEMM + fused bias/IntGELU/minmax --
// K split into 32 slots of 32. LDS: A-ring 4 slots @16KB + B-ring 4 slots @16KB = 128KB.
// Slot layout: [256 rows][4 chunks of 16B], chunk swizzled c' = c ^ ((row>>1)&3)
// (applied on the GLOBAL source within each 1KB gload_lds window + on ds_read addr;
//  LDS dest stays linear per rule #21). Per phase: 12 ds_read_b128, stage slot s+3,
// vmcnt(8)->barrier (counted, never 0 mid-loop), 32 MFMA, lgkmcnt(0)->barrier (WAR guard).
__global__ __launch_bounds__(512, 2) void k_gemm(
    const bf16* __restrict__ A, const bf16* __restrict__ B,
    const float* __restrict__ pb, const float* __restrict__ pbg,
    const float* __restrict__ pcg, const float* __restrict__ psh,
    const float* __restrict__ posf,
    float* __restrict__ out, unsigned* __restrict__ mm) {
  __shared__ __align__(16) char smem[131072];
  __shared__ float smn[8], smx[8];
  const int t = threadIdx.x;
  const int wave = t >> 6, lane = t & 63;
  const int wm = wave >> 2, wn = wave & 3;          // 2x4 wave grid
  const int r16 = lane & 15, q4 = lane >> 4;
  // bijective XCD swizzle (512 blocks, 8 XCDs, 64 per XCD; 4 M-rows/XCD for A reuse)
  const int lin = blockIdx.x;
  const int wid = (lin & 7) * 64 + (lin >> 3);
  const int brow = (wid >> 4) * 256, bcol = (wid & 15) * 256;
  // staging per-thread constants (pre-swizzled global source within 1KB window)
  const int lr = lane >> 2;                          // row within 16-row window
  const int lc = (lane & 3) ^ ((lane >> 3) & 3);     // swizzled 16B chunk
  const int idx0 = wave * 2;
  // ds_read per-thread constants
  const int cpr = q4 ^ ((r16 >> 1) & 3);
  const int aoff0 = (wm * 128 + r16) * 64 + cpr * 16;
  const int boff0 = 65536 + (wn * 64 + r16) * 64 + cpr * 16;
  f32x4 acc[8][4] = {};

  auto stage = [&](int s) {
    const int ring = (s & 3) * SLOT_BYTES;
    const size_t kof = (size_t)s * 32;
#pragma unroll
    for (int j = 0; j < 2; ++j) {
      const int idx = idx0 + j;
      gload_lds16(A + (size_t)(brow + idx * 16 + lr) * K_DIM + kof + lc * 8,
                  smem + ring + idx * 1024);
      gload_lds16(B + (size_t)(bcol + idx * 16 + lr) * K_DIM + kof + lc * 8,
                  smem + 65536 + ring + idx * 1024);
    }
  };

#define PHASE(S, WAITASM, DO_STAGE)                                              \
  do {                                                                           \
    const int ring = ((S) & 3) * SLOT_BYTES;                                     \
    bf16x8 af[8], bfr[4];                                                        \
    _Pragma("unroll") for (int mf = 0; mf < 8; ++mf)                             \
        af[mf] = *(const bf16x8*)(smem + ring + aoff0 + mf * 1024);              \
    _Pragma("unroll") for (int nf = 0; nf < 4; ++nf)                             \
        bfr[nf] = *(const bf16x8*)(smem + ring + boff0 + nf * 1024);             \
    if (DO_STAGE) stage((S) + 3);                                                \
    asm volatile(WAITASM ::: "memory");                                          \
    asm volatile("s_barrier" ::: "memory");                                      \
    __builtin_amdgcn_s_setprio(1);                                               \
    _Pragma("unroll") for (int mf = 0; mf < 8; ++mf)                             \
        _Pragma("unroll") for (int nf = 0; nf < 4; ++nf)                         \
            acc[mf][nf] = __builtin_amdgcn_mfma_f32_16x16x32_bf16(               \
                af[mf], bfr[nf], acc[mf][nf], 0, 0, 0);                          \
    __builtin_amdgcn_s_setprio(0);                                               \
    asm volatile("s_waitcnt lgkmcnt(0)" ::: "memory");                           \
    asm volatile("s_barrier" ::: "memory");                                      \
  } while (0)

  // prologue: stage slots 0..2 (12 loads), wait until slot 0 complete everywhere
  stage(0); stage(1); stage(2);
  asm volatile("s_waitcnt vmcnt(8)" ::: "memory");
  asm volatile("s_barrier" ::: "memory");

  for (int s = 0; s < 29; ++s) PHASE(s, "s_waitcnt vmcnt(8)", true);
  PHASE(29, "s_waitcnt vmcnt(4)", false);
  PHASE(30, "s_waitcnt vmcnt(0)", false);
  PHASE(31, "s_waitcnt vmcnt(0)", false);
#undef PHASE

  // epilogue: bias add + IntGELU, write pre-requant value, track min/max
  float mn = 0.f, mx = 0.f;
#pragma unroll
  for (int nf = 0; nf < 4; ++nf) {
    const int ch = bcol + wn * 64 + nf * 16 + r16;
    const float bi = pb[ch], bg = pbg[ch], cg = pcg[ch], sh = psh[ch], osf = posf[ch];
#pragma unroll
    for (int mf = 0; mf < 8; ++mf) {
      const int row0 = brow + wm * 128 + mf * 16 + q4 * 4;
#pragma unroll
      for (int r = 0; r < 4; ++r) {
        const float x0 = acc[mf][nf][r] + bi;                    // out_int (int-valued fp32)
        const float sgn = (x0 > 0.f) ? 1.f : ((x0 < 0.f) ? -1.f : 0.f);
        const float ai = fminf(fabsf(x0), -bg);
        const float tt = ai + bg;
        const float y = floorf((sgn * (tt * tt + cg)) * 6.103515625e-05f);  // /2^14, floor
        const float xval = (x0 * (y + sh)) * osf;
        mn = fminf(mn, xval);
        mx = fmaxf(mx, xval);
        out[(size_t)(row0 + r) * N_DIM + ch] = xval;
      }
    }
  }
  for (int off = 32; off > 0; off >>= 1) {
    mn = fminf(mn, __shfl_down(mn, off));
    mx = fmaxf(mx, __shfl_down(mx, off));
  }
  if (lane == 0) { smn[wave] = mn; smx[wave] = mx; }
  __syncthreads();
  if (t == 0) {
    mn = fminf(fminf(fminf(smn[0], smn[1]), fminf(smn[2], smn[3])),
               fminf(fminf(smn[4], smn[5]), fminf(smn[6], smn[7])));
    mx = fmaxf(fmaxf(fmaxf(smx[0], smx[1]), fmaxf(smx[2], smx[3])),
               fmaxf(fmaxf(smx[4], smx[5]), fmaxf(smx[6], smx[7])));
    atomicMin(&mm[0], enc(mn));
    atomicMax(&mm[1], enc(mx));
  }
}

// -------- Kernel D: global requant (QuantAct / FixedPointMul), in place on d_out --------
__global__ __launch_bounds__(256) void k_requant(
    float* __restrict__ out, const float* __restrict__ posf,
    const unsigned* __restrict__ mm) {
  const float xmn = dec(mm[0]);
  const float xmx = dec(mm[1]);
  const float asf = fmaxf(fmaxf(fabsf(xmn), fabsf(xmx)), 1e-8f) / 127.f;
  const size_t i = ((size_t)blockIdx.x * 256 + threadIdx.x) * 4;
  float4 xv = *(float4*)(out + i);
  const int o0 = (int)(i & (N_DIM - 1));
  const float4 sf4 = *(const float4*)(posf + o0);
  float xs[4] = {xv.x, xv.y, xv.z, xv.w};
  float ps[4] = {sf4.x, sf4.y, sf4.z, sf4.w};
  float rs[4];
#pragma unroll
  for (int r = 0; r < 4; ++r) {
    const float z = rintf(xs[r] / ps[r]);
    int e;
    const float mfr = frexpf(ps[r] / asf, &e);
    const float mi = floorf(mfr * 2147483648.f + 0.5f);
    float q = rintf((z * mi) * ldexpf(1.0f, e - 31));
    q = fminf(fmaxf(q, -128.f), 127.f);
    rs[r] = q * asf;
  }
  xv.x = rs[0]; xv.y = rs[1]; xv.z = rs[2]; xv.w = rs[3];
  *(float4*)(out + i) = xv;
  if (blockIdx.x == 0 && threadIdx.x == 0) out[OUT_ELEMS] = asf;  // trailing sf scalar
}

extern "C" void kernel_launch(void* const* d_in, const int* in_sizes, int n_in,
                              void* d_out, int out_size, void* d_ws, size_t ws_size,
                              hipStream_t stream) {
  const float* x = (const float*)d_in[0];
  const float* psf = (const float*)d_in[1];
  const float* w = (const float*)d_in[2];
  const float* bias = (const float*)d_in[3];
  float* out = (float*)d_out;
  char* ws = (char*)d_ws;

  bf16* wq = (bf16*)ws;                                   // 8 MiB
  bf16* xq = (bf16*)(ws + 8388608);                       // 16 MiB
  float* pb = (float*)(ws + 25165824);                    // 5 x 16 KiB param arrays
  float* pbg = pb + N_DIM;
  float* pcg = pb + 2 * N_DIM;
  float* psh = pb + 3 * N_DIM;
  float* posf = pb + 4 * N_DIM;
  unsigned* mm = (unsigned*)(ws + 25165824 + 5 * 16384);  // 2 x u32 min/max

  k_prep_w<<<dim3(N_DIM), dim3(256), 0, stream>>>(w, bias, psf, wq, pb, pbg, pcg, psh, posf, mm);
  k_quant_x<<<dim3((M_DIM * K_DIM) / (256 * 4)), dim3(256), 0, stream>>>(x, psf, xq);
  k_gemm<<<dim3(512), dim3(512), 0, stream>>>(xq, wq, pb, pbg, pcg, psh, posf, out, mm);
  k_requant<<<dim3(OUT_ELEMS / (256 * 4)), dim3(256), 0, stream>>>(out, posf, mm);
}

// Round 4
// 119.299 us; speedup vs baseline: 1.4932x; 1.2029x over previous
//
#include <hip/hip_runtime.h>
#include <hip/hip_bf16.h>

typedef __attribute__((ext_vector_type(4))) int i32x4;

#define M_DIM 8192
#define K_DIM 1024
#define N_DIM 4096
#define OUT_ELEMS (M_DIM * (size_t)N_DIM)

static __device__ __forceinline__ void gload_lds16(const void* g, void* l) {
  __builtin_amdgcn_global_load_lds((__attribute__((address_space(1))) void*)g,
                                   (__attribute__((address_space(3))) void*)l,
                                   16, 0, 0);
}

// monotone float<->uint encoding for atomic min/max
static __device__ __forceinline__ unsigned enc(float f) {
  unsigned u = __float_as_uint(f);
  return (u >> 31) ? ~u : (u ^ 0x80000000u);
}
static __device__ __forceinline__ float dec(unsigned e) {
  return (e >> 31) ? __uint_as_float(e ^ 0x80000000u) : __uint_as_float(~e);
}

// pack 4 int-valued floats into one i32 as signed bytes (unsigned shifts: no UB)
static __device__ __forceinline__ int pack4(float a, float b, float c, float d) {
  unsigned v0 = (unsigned)(int)a & 255u, v1 = (unsigned)(int)b & 255u;
  unsigned v2 = (unsigned)(int)c & 255u, v3 = (unsigned)(int)d & 255u;
  return (int)(v0 | (v1 << 8) | (v2 << 16) | (v3 << 24));
}

// -------- Kernel A: per-channel weight quant (int8) + IntGELU per-channel constants ----
__global__ __launch_bounds__(256) void k_prep_w(
    const float* __restrict__ w, const float* __restrict__ bias,
    const float* __restrict__ prev_sf,
    int* __restrict__ wq, float* __restrict__ pb, float* __restrict__ pbg,
    float* __restrict__ pcg, float* __restrict__ psh, float* __restrict__ posf,
    unsigned* __restrict__ mm) {
  const int o = blockIdx.x;
  const int t = threadIdx.x;
  const float4 wv = *(const float4*)(w + (size_t)o * K_DIM + t * 4);
  float m = fmaxf(fmaxf(fabsf(wv.x), fabsf(wv.y)), fmaxf(fabsf(wv.z), fabsf(wv.w)));
  __shared__ float red[256];
  red[t] = m;
  __syncthreads();
  for (int s = 128; s > 0; s >>= 1) {
    if (t < s) red[t] = fmaxf(red[t], red[t + s]);
    __syncthreads();
  }
  const float fc = fmaxf(red[0], 1e-8f) / 127.f;  // fc_sf[o]
  wq[o * (K_DIM / 4) + t] = pack4(
      fminf(fmaxf(rintf(wv.x / fc), -127.f), 126.f),
      fminf(fmaxf(rintf(wv.y / fc), -127.f), 126.f),
      fminf(fmaxf(rintf(wv.z / fc), -127.f), 126.f),
      fminf(fmaxf(rintf(wv.w / fc), -127.f), 126.f));
  if (t == 0) {
    const float psf = prev_sf[0];
    const float bsf = fc * psf;  // bias_sf
    float bi = fminf(fmaxf(rintf(bias[o] / bsf), -2147483647.f), 2147483646.f);
    const float sfe = bsf / 1.4142f;
    const float bg = floorf(-1.769f / sfe);
    const float cF = (float)(1.0 / -0.2888);
    const float se2 = sfe * sfe;
    const float cg = floorf(cF / se2);
    const float sig = (se2 * -0.2888f) * 16384.f;   // sf_e^2 * a * 2^14
    const float sh = floorf(1.0f / sig);            // shift (negative)
    const float osf = (bsf * sig) * 0.5f;           // out_sf (negative)
    pb[o] = bi; pbg[o] = bg; pcg[o] = cg; psh[o] = sh; posf[o] = osf;
  }
  if (o == 0 && t == 0) {  // init global min/max (encoded 0.0f)
    mm[0] = 0x80000000u;
    mm[1] = 0x80000000u;
  }
}

// -------- Kernel B: activation -> exact-integer int8 --------
__global__ __launch_bounds__(256) void k_quant_x(
    const float* __restrict__ x, const float* __restrict__ prev_sf,
    int4* __restrict__ xq) {
  const size_t i = ((size_t)blockIdx.x * 256 + threadIdx.x) * 16;
  const float inv = 1.0f / prev_sf[0];
  const float4 v0 = *(const float4*)(x + i);
  const float4 v1 = *(const float4*)(x + i + 4);
  const float4 v2 = *(const float4*)(x + i + 8);
  const float4 v3 = *(const float4*)(x + i + 12);
  int4 q;
  q.x = pack4(rintf(v0.x * inv), rintf(v0.y * inv), rintf(v0.z * inv), rintf(v0.w * inv));
  q.y = pack4(rintf(v1.x * inv), rintf(v1.y * inv), rintf(v1.z * inv), rintf(v1.w * inv));
  q.z = pack4(rintf(v2.x * inv), rintf(v2.y * inv), rintf(v2.z * inv), rintf(v2.w * inv));
  q.w = pack4(rintf(v3.x * inv), rintf(v3.y * inv), rintf(v3.z * inv), rintf(v3.w * inv));
  xq[i / 16] = q;
}

// -------- Kernel C: int8 MFMA GEMM (exact i32) + fused bias/IntGELU/minmax, f32 out ----
// 256x256 tile, 8 waves (2Mx4N), K sliced into 8 slots of 128 bytes. LDS ring-2:
// A 2x32KB + B 2x32KB = 128KB. Slot row = 128B (8 chunks of 16B), chunk swizzled
// c' = c ^ (row&7) via pre-swizzled global source (LDS dest linear, rule #21).
__global__ __launch_bounds__(512, 2) void k_gemm(
    const char* __restrict__ A, const char* __restrict__ B,
    const float* __restrict__ pb, const float* __restrict__ pbg,
    const float* __restrict__ pcg, const float* __restrict__ psh,
    const float* __restrict__ posf,
    float* __restrict__ out, unsigned* __restrict__ mm) {
  __shared__ __align__(16) char smem[131072];
  __shared__ float smn[8], smx[8];
  const int t = threadIdx.x;
  const int wave = t >> 6, lane = t & 63;
  const int wm = wave >> 2, wn = wave & 3;          // 2x4 wave grid
  const int r16 = lane & 15, q4 = lane >> 4;
  // XCD-local 8x8 (M,N) sub-grid: per-XCD working set = 2MB A + 2MB B = 4MB = L2
  const int lin = blockIdx.x;
  const int xcd = lin & 7, j = lin >> 3;
  const int mblk = (xcd >> 1) * 8 + (j >> 3);       // [0,32)
  const int nblk = (xcd & 1) * 8 + (j & 7);         // [0,16)
  const int brow = mblk * 256, bcol = nblk * 256;
  // staging constants: window = 8 rows x 128B; source chunk pre-swizzled
  const int sr = lane >> 3;                          // row in window
  const int sc = (lane & 7) ^ (sr & 7);              // swizzled 16B chunk
  // ds_read constants
  const int cs0 = (q4 ^ (r16 & 7)) * 16;             // kk=0 chunk byte
  const int cs1 = ((4 + q4) ^ (r16 & 7)) * 16;       // kk=1 chunk byte
  const int aB = (wm * 128 + r16) * 128;
  const int bB = 65536 + (wn * 64 + r16) * 128;
  i32x4 acc[8][4] = {};

  auto stage = [&](int s) {
    const int ring = (s & 1) << 15;
    const int kof = s * 128;
#pragma unroll
    for (int jw = 0; jw < 4; ++jw) {
      const int rowg = wave * 32 + jw * 8;
      gload_lds16(A + (size_t)(brow + rowg + sr) * K_DIM + kof + sc * 16,
                  smem + ring + rowg * 128);
      gload_lds16(B + (size_t)(bcol + rowg + sr) * K_DIM + kof + sc * 16,
                  smem + 65536 + ring + rowg * 128);
    }
  };

  stage(0);
  asm volatile("s_waitcnt vmcnt(0)" ::: "memory");
  __builtin_amdgcn_s_barrier();

  for (int s = 0; s < 8; ++s) {
    if (s < 7) stage(s + 1);
    const int ring = (s & 1) << 15;
#pragma unroll
    for (int kk = 0; kk < 2; ++kk) {
      const int cs = kk ? cs1 : cs0;
      i32x4 af[8], bfr[4];
#pragma unroll
      for (int nf = 0; nf < 4; ++nf)
        bfr[nf] = *(const i32x4*)(smem + ring + bB + nf * 2048 + cs);
#pragma unroll
      for (int mf = 0; mf < 8; ++mf)
        af[mf] = *(const i32x4*)(smem + ring + aB + mf * 2048 + cs);
      __builtin_amdgcn_s_setprio(1);
#pragma unroll
      for (int mf = 0; mf < 8; ++mf)
#pragma unroll
        for (int nf = 0; nf < 4; ++nf)
          acc[mf][nf] = __builtin_amdgcn_mfma_i32_16x16x64_i8(af[mf], bfr[nf], acc[mf][nf], 0, 0, 0);
      __builtin_amdgcn_s_setprio(0);
    }
    asm volatile("s_waitcnt vmcnt(0) lgkmcnt(0)" ::: "memory");
    __builtin_amdgcn_s_barrier();
  }

  // epilogue: bias add + IntGELU, write pre-requant f32 value, track min/max
  float mn = 0.f, mx = 0.f;
#pragma unroll
  for (int nf = 0; nf < 4; ++nf) {
    const int ch = bcol + wn * 64 + nf * 16 + r16;
    const float bi = pb[ch], bg = pbg[ch], cg = pcg[ch], sh = psh[ch], osf = posf[ch];
#pragma unroll
    for (int mf = 0; mf < 8; ++mf) {
      const int row0 = brow + wm * 128 + mf * 16 + q4 * 4;
#pragma unroll
      for (int r = 0; r < 4; ++r) {
        const float x0 = (float)acc[mf][nf][r] + bi;             // out_int (exact, <2^24)
        const float sgn = (x0 > 0.f) ? 1.f : ((x0 < 0.f) ? -1.f : 0.f);
        const float ai = fminf(fabsf(x0), -bg);
        const float tt = ai + bg;
        const float y = floorf((sgn * (tt * tt + cg)) * 6.103515625e-05f);  // /2^14
        const float xval = (x0 * (y + sh)) * osf;
        mn = fminf(mn, xval);
        mx = fmaxf(mx, xval);
        out[(size_t)(row0 + r) * N_DIM + ch] = xval;
      }
    }
  }
  for (int off = 32; off > 0; off >>= 1) {
    mn = fminf(mn, __shfl_down(mn, off));
    mx = fmaxf(mx, __shfl_down(mx, off));
  }
  if (lane == 0) { smn[wave] = mn; smx[wave] = mx; }
  __syncthreads();
  if (t == 0) {
    mn = fminf(fminf(fminf(smn[0], smn[1]), fminf(smn[2], smn[3])),
               fminf(fminf(smn[4], smn[5]), fminf(smn[6], smn[7])));
    mx = fmaxf(fmaxf(fmaxf(smx[0], smx[1]), fmaxf(smx[2], smx[3])),
               fmaxf(fmaxf(smx[4], smx[5]), fmaxf(smx[6], smx[7])));
    atomicMin(&mm[0], enc(mn));
    atomicMax(&mm[1], enc(mx));
  }
}

// -------- Kernel D: global requant (QuantAct / FixedPointMul), in place on d_out ------
// (R2-proven version: exact f32 read, per-element frexpf)
__global__ __launch_bounds__(256) void k_requant(
    float* __restrict__ out, const float* __restrict__ posf,
    const unsigned* __restrict__ mm) {
  const float xmn = dec(mm[0]);
  const float xmx = dec(mm[1]);
  const float asf = fmaxf(fmaxf(fabsf(xmn), fabsf(xmx)), 1e-8f) / 127.f;
  const size_t i = ((size_t)blockIdx.x * 256 + threadIdx.x) * 4;
  float4 xv = *(float4*)(out + i);
  const int o0 = (int)(i & (N_DIM - 1));
  const float4 sf4 = *(const float4*)(posf + o0);
  float xs[4] = {xv.x, xv.y, xv.z, xv.w};
  float ps[4] = {sf4.x, sf4.y, sf4.z, sf4.w};
  float rs[4];
#pragma unroll
  for (int r = 0; r < 4; ++r) {
    const float z = rintf(xs[r] / ps[r]);
    int e;
    const float mfr = frexpf(ps[r] / asf, &e);
    const float mi = floorf(mfr * 2147483648.f + 0.5f);
    float q = rintf((z * mi) * ldexpf(1.0f, e - 31));
    q = fminf(fmaxf(q, -128.f), 127.f);
    rs[r] = q * asf;
  }
  xv.x = rs[0]; xv.y = rs[1]; xv.z = rs[2]; xv.w = rs[3];
  *(float4*)(out + i) = xv;
  if (blockIdx.x == 0 && threadIdx.x == 0) out[OUT_ELEMS] = asf;  // trailing sf scalar
}

extern "C" void kernel_launch(void* const* d_in, const int* in_sizes, int n_in,
                              void* d_out, int out_size, void* d_ws, size_t ws_size,
                              hipStream_t stream) {
  const float* x = (const float*)d_in[0];
  const float* psf = (const float*)d_in[1];
  const float* w = (const float*)d_in[2];
  const float* bias = (const float*)d_in[3];
  float* out = (float*)d_out;
  char* ws = (char*)d_ws;

  int* wq = (int*)ws;                                     // 4 MiB (i8)
  char* xq = ws + 4194304;                                // 8 MiB (i8)
  float* pb = (float*)(ws + 12582912);                    // 5 x 16 KiB
  float* pbg = pb + N_DIM;
  float* pcg = pb + 2 * N_DIM;
  float* psh = pb + 3 * N_DIM;
  float* posf = pb + 4 * N_DIM;
  unsigned* mm = (unsigned*)(pb + 5 * N_DIM + 16);        // 2 x u32 min/max

  k_prep_w<<<dim3(N_DIM), dim3(256), 0, stream>>>(w, bias, psf, wq, pb, pbg, pcg, psh, posf, mm);
  k_quant_x<<<dim3((M_DIM * K_DIM) / (256 * 16)), dim3(256), 0, stream>>>(x, psf, (int4*)xq);
  k_gemm<<<dim3(512), dim3(512), 0, stream>>>(xq, (const char*)wq, pb, pbg, pcg, psh, posf, out, mm);
  k_requant<<<dim3((int)(OUT_ELEMS / (256 * 4))), dim3(256), 0, stream>>>(out, posf, mm);
}